// Round 3
// baseline (74.713 us; speedup 1.0000x reference)
//
#include <hip/hip_runtime.h>

// Problem constants (reference: B=64, T=4096, H=512)
#define T_LEN 4096
#define H_LEN 512
#define B_LEN 64
#define NGBLK (T_LEN / 64)   // 64 g-producer blocks == 64 dot rows

// Closed form of the diagonal linear scan:
//   z[bi] = sum_t x[bi,t]*g[t] + K
//   g[t]  = sum_j w_j b_j a_j^{T-1-t}
//   K     = sum_j w_j c_j (1-a_j^T)/(1-a_j) + e
//
// Single fused launch, 65 blocks (all co-resident on 256 CUs):
//   blocks 0..63 : build a 64-wide g chunk (4 threads/t x 128 j each),
//                  then soft-barrier, then dot their x row with g.
//                  x row is prefetched into VGPRs BEFORE phase 1 so the
//                  1 MiB HBM read hides behind the exp2 work.
//   block 64     : coordinator. Init barrier counter C=0, compute K in fp64
//                  (1/(1-a) amplifies up to 1000x), publish flag F=1.
// Barrier is init-free w.r.t. the 0xAA ws poison: nobody touches C until
// F==1, and F is only set to 1 by block 64 after initializing C.
__global__ __launch_bounds__(256) void fused_kernel(
    const float* __restrict__ x,   // [B_LEN, T_LEN]
    const float* __restrict__ a,
    const float* __restrict__ b,
    const float* __restrict__ c,
    const float* __restrict__ w,
    const float* __restrict__ e,
    float* __restrict__ g,         // ws: T_LEN floats
    float* __restrict__ Kc,        // ws: 1 float
    unsigned int* __restrict__ C,  // ws: barrier counter
    unsigned int* __restrict__ F,  // ws: barrier flag
    float* __restrict__ z)         // [B_LEN]
{
    const int tid = threadIdx.x;
    const int blk = blockIdx.x;

    if (blk == NGBLK) {
        // --- coordinator: init C, compute K (fp64), publish F ---
        if (tid == 0)
            __hip_atomic_store(C, 0u, __ATOMIC_RELEASE, __HIP_MEMORY_SCOPE_AGENT);
        __shared__ double red[256];
        double s = 0.0;
        for (int j = tid; j < H_LEN; j += 256) {
            const double aj  = (double)a[j];
            const double geo = (1.0 - pow(aj, (double)T_LEN)) / (1.0 - aj);
            s += (double)w[j] * (double)c[j] * geo;
        }
        red[tid] = s;
        __syncthreads();
        for (int off = 128; off > 0; off >>= 1) {
            if (tid < off) red[tid] += red[tid + off];
            __syncthreads();
        }
        if (tid == 0) {
            Kc[0] = (float)(red[0] + (double)e[0]);
            __threadfence();
            __hip_atomic_store(F, 1u, __ATOMIC_RELEASE, __HIP_MEMORY_SCOPE_AGENT);
        }
        return;
    }

    // --- phase 0: prefetch my x row into VGPRs (consumed after barrier) ---
    const float4* __restrict__ xr = (const float4*)(x + (size_t)blk * T_LEN);
    const float4 xv0 = xr[tid];
    const float4 xv1 = xr[tid + 256];
    const float4 xv2 = xr[tid + 512];
    const float4 xv3 = xr[tid + 768];

    // --- phase 1: build g[blk*64 .. blk*64+63] ---
    __shared__ float wb[H_LEN];
    __shared__ float l2a[H_LEN];
    for (int j = tid; j < H_LEN; j += 256) {
        wb[j]  = w[j] * b[j];
        l2a[j] = log2f(a[j]);
    }
    __syncthreads();
    const int   tt = tid & 63;      // t within chunk
    const int   jq = tid >> 6;      // j quadrant (== wave id)
    const int   t  = blk * 64 + tt;
    const float k  = (float)(T_LEN - 1 - t);
    const int   j0 = jq * (H_LEN / 4);
    float s = 0.f;
#pragma unroll 8
    for (int jj = 0; jj < H_LEN / 4; ++jj) {
        const int j = j0 + jj;
        s += wb[j] * exp2f(k * l2a[j]);  // wave-uniform LDS reads: broadcast
    }
    __shared__ float part[4][64];
    part[jq][tt] = s;
    __syncthreads();
    if (tid < 64)
        g[blk * 64 + tid] = part[0][tid] + part[1][tid] + part[2][tid] + part[3][tid];

    // --- soft barrier across the 64 g-producer blocks ---
    __syncthreads();
    if (tid == 0) {
        __threadfence();  // publish my g chunk (device scope)
        while (__hip_atomic_load(F, __ATOMIC_ACQUIRE, __HIP_MEMORY_SCOPE_AGENT) != 1u) {}
        __hip_atomic_fetch_add(C, 1u, __ATOMIC_ACQ_REL, __HIP_MEMORY_SCOPE_AGENT);
        while (__hip_atomic_load(C, __ATOMIC_ACQUIRE, __HIP_MEMORY_SCOPE_AGENT) != (unsigned)NGBLK) {}
    }
    __syncthreads();
    __threadfence();  // acquire side for all threads: no stale g/Kc in L1

    // --- phase 2: dot(x_row, g) + K ---
    const float4* __restrict__ gv = (const float4*)g;
    const float4 g0 = gv[tid];
    const float4 g1 = gv[tid + 256];
    const float4 g2 = gv[tid + 512];
    const float4 g3 = gv[tid + 768];
    float d = xv0.x * g0.x + xv0.y * g0.y + xv0.z * g0.z + xv0.w * g0.w
            + xv1.x * g1.x + xv1.y * g1.y + xv1.z * g1.z + xv1.w * g1.w
            + xv2.x * g2.x + xv2.y * g2.y + xv2.z * g2.z + xv2.w * g2.w
            + xv3.x * g3.x + xv3.y * g3.y + xv3.z * g3.z + xv3.w * g3.w;
#pragma unroll
    for (int off = 32; off > 0; off >>= 1)
        d += __shfl_down(d, off, 64);
    __shared__ float wsum[4];
    if ((tid & 63) == 0) wsum[tid >> 6] = d;
    __syncthreads();
    if (tid == 0)
        z[blk] = wsum[0] + wsum[1] + wsum[2] + wsum[3] + Kc[0];
}

extern "C" void kernel_launch(void* const* d_in, const int* in_sizes, int n_in,
                              void* d_out, int out_size, void* d_ws, size_t ws_size,
                              hipStream_t stream) {
    const float* x = (const float*)d_in[0];  // [B,T]
    const float* a = (const float*)d_in[1];  // [H]
    const float* b = (const float*)d_in[2];  // [H]
    const float* c = (const float*)d_in[3];  // [H]
    const float* w = (const float*)d_in[4];  // [H]
    const float* e = (const float*)d_in[5];  // [1]
    float* out = (float*)d_out;              // [B] fp32

    float*        g  = (float*)d_ws;             // T_LEN floats
    float*        Kc = g + T_LEN;                // 1 float
    unsigned int* C  = (unsigned int*)(Kc + 1);  // barrier counter
    unsigned int* F  = C + 1;                    // barrier flag

    fused_kernel<<<NGBLK + 1, 256, 0, stream>>>(x, a, b, c, w, e, g, Kc, C, F, out);
}

// Round 4
// 70.702 us; speedup vs baseline: 1.0567x; 1.0567x over previous
//
#include <hip/hip_runtime.h>

// Problem constants (reference: B=64, T=4096, H=512)
#define T_LEN 4096
#define H_LEN 512
#define B_LEN 64
#define NCHUNK (T_LEN / 64)   // 64 t-chunks, one block each

// Closed form of the diagonal linear scan:
//   z[bi] = sum_t x[bi,t]*g[t] + K
//   g[t]  = sum_j w_j b_j a_j^{T-1-t}
//   K     = sum_j w_j c_j (1-a_j^T)/(1-a_j) + e
//
// Round-3 lesson: inter-block sync (soft barrier) regressed. This version has
// NO inter-block dependency: block p computes g for its own 64-wide t-chunk
// in LDS, then immediately dots that chunk against the same t-slice of all
// 64 x rows, emitting partials[row][p]. g never touches global memory.
// Kernel 2 (1 block) does the fp64 geometric-series K and the 64x64 partial
// reduction.
__global__ __launch_bounds__(256) void chunk_kernel(
    const float* __restrict__ x,   // [B_LEN, T_LEN]
    const float* __restrict__ a,
    const float* __restrict__ b,
    const float* __restrict__ w,
    float* __restrict__ partials)  // ws: [B_LEN][NCHUNK]
{
    const int tid = threadIdx.x;
    const int blk = blockIdx.x;          // t-chunk index

    // --- phase A: build g[blk*64 .. blk*64+63] into LDS ---
    __shared__ float wb[H_LEN];
    __shared__ float l2a[H_LEN];
    for (int j = tid; j < H_LEN; j += 256) {
        wb[j]  = w[j] * b[j];
        l2a[j] = log2f(a[j]);
    }
    __syncthreads();
    const int   tt = tid & 63;           // t within chunk
    const int   jq = tid >> 6;           // j quadrant (== wave id)
    const float k  = (float)(T_LEN - 1 - (blk * 64 + tt));
    const int   j0 = jq * (H_LEN / 4);
    float s = 0.f;
#pragma unroll 8
    for (int jj = 0; jj < H_LEN / 4; ++jj) {
        const int j = j0 + jj;
        s += wb[j] * exp2f(k * l2a[j]);  // wave-uniform LDS reads: broadcast
    }
    __shared__ float part[4][64];
    part[jq][tt] = s;
    __syncthreads();
    __shared__ float gloc[64];
    if (tid < 64)
        gloc[tid] = part[0][tid] + part[1][tid] + part[2][tid] + part[3][tid];
    __syncthreads();

    // --- phase B: dot this t-chunk against all 64 rows of x ---
    // thread = row*4 + q; each thread covers 16 t's (4 float4 loads).
    const int row = tid >> 2;
    const int q   = tid & 3;
    const float4* __restrict__ xp =
        (const float4*)(x + (size_t)row * T_LEN + blk * 64 + q * 16);
    const float4* __restrict__ gl = (const float4*)gloc;  // LDS
    float d = 0.f;
#pragma unroll
    for (int i = 0; i < 4; ++i) {
        const float4 xv = xp[i];
        const float4 gv = gl[q * 4 + i];  // 2-way bank alias max: free
        d += xv.x * gv.x + xv.y * gv.y + xv.z * gv.z + xv.w * gv.w;
    }
    // reduce the 4 q-threads (same wave: tid^1, tid^2 preserve row)
    d += __shfl_xor(d, 1, 64);
    d += __shfl_xor(d, 2, 64);
    if (q == 0) partials[row * NCHUNK + blk] = d;
}

// Kernel 2: K (fp64 — 1/(1-a) amplifies up to 1000x) + partial reduction.
__global__ __launch_bounds__(256) void finish_kernel(
    const float* __restrict__ a,
    const float* __restrict__ c,
    const float* __restrict__ w,
    const float* __restrict__ e,
    const float* __restrict__ partials,  // [B_LEN][NCHUNK]
    float* __restrict__ z)               // [B_LEN]
{
    const int tid = threadIdx.x;
    __shared__ double red[256];
    double s = 0.0;
    for (int j = tid; j < H_LEN; j += 256) {
        const double aj  = (double)a[j];
        const double geo = (1.0 - pow(aj, (double)T_LEN)) / (1.0 - aj);
        s += (double)w[j] * (double)c[j] * geo;
    }
    red[tid] = s;
    __syncthreads();
    for (int off = 128; off > 0; off >>= 1) {
        if (tid < off) red[tid] += red[tid + off];
        __syncthreads();
    }
    __shared__ float Ksh;
    if (tid == 0) Ksh = (float)(red[0] + (double)e[0]);
    __syncthreads();
    if (tid < B_LEN) {
        const float4* __restrict__ pp = (const float4*)(partials + tid * NCHUNK);
        float acc = 0.f;
#pragma unroll
        for (int i = 0; i < NCHUNK / 4; ++i) {
            const float4 v = pp[i];
            acc += v.x + v.y + v.z + v.w;
        }
        z[tid] = acc + Ksh;
    }
}

extern "C" void kernel_launch(void* const* d_in, const int* in_sizes, int n_in,
                              void* d_out, int out_size, void* d_ws, size_t ws_size,
                              hipStream_t stream) {
    const float* x = (const float*)d_in[0];  // [B,T]
    const float* a = (const float*)d_in[1];  // [H]
    const float* b = (const float*)d_in[2];  // [H]
    const float* c = (const float*)d_in[3];  // [H]
    const float* w = (const float*)d_in[4];  // [H]
    const float* e = (const float*)d_in[5];  // [1]
    float* out = (float*)d_out;              // [B] fp32

    float* partials = (float*)d_ws;          // B_LEN*NCHUNK floats (16 KB)

    chunk_kernel<<<NCHUNK, 256, 0, stream>>>(x, a, b, w, partials);
    finish_kernel<<<1, 256, 0, stream>>>(a, c, w, e, partials, out);
}